// Round 1
// baseline (349.206 us; speedup 1.0000x reference)
//
#include <hip/hip_runtime.h>

// DynamicMemoryCell: B=8, N=2048, IN=256, MEM=256, CTX=128
// out0 = new_memory [8,2048,256] f32 ; out1 = attention_probs [8,2048,2048] f32
// Skip Wv/value/context entirely (dead in reference).

typedef _Float16 half8 __attribute__((ext_vector_type(8)));
typedef float floatx4 __attribute__((ext_vector_type(4)));

#define MFMA16(a, b, c) __builtin_amdgcn_mfma_f32_16x16x32_f16((a), (b), (c), 0, 0, 0)

// ws layout (units: _Float16)
#define OFF_WQH 0
#define OFF_WQL 32768
#define OFF_WKH 65536
#define OFF_WKL 98304
#define OFF_WUH 131072
#define OFF_WRH 262144
#define OFF_WCH 393216
#define OFF_Q   524288
#define OFF_K   2621440
// total = 4718592 halves = 9,437,184 bytes

// ---------------------------------------------------------------- K0: weights fp32 -> fp16 (hi/lo split for Wq/Wk)
__global__ __launch_bounds__(256) void k0_convert(
    const float* __restrict__ Wq, const float* __restrict__ Wk,
    const float* __restrict__ Wu, const float* __restrict__ Wr,
    const float* __restrict__ Wc, _Float16* __restrict__ ws)
{
  int i = blockIdx.x * 256 + threadIdx.x;   // grid covers 458752 exactly
  if (i < 32768) {
    float w = Wq[i];
    _Float16 h = (_Float16)w;
    ws[OFF_WQH + i] = h;
    ws[OFF_WQL + i] = (_Float16)(w - (float)h);
  } else if (i < 65536) {
    int j = i - 32768;
    float w = Wk[j];
    _Float16 h = (_Float16)w;
    ws[OFF_WKH + j] = h;
    ws[OFF_WKL + j] = (_Float16)(w - (float)h);
  } else {
    int j = i - 65536;                       // 0 .. 393215
    if (j < 131072)      ws[OFF_WUH + j]            = (_Float16)Wu[j];
    else if (j < 262144) ws[OFF_WRH + (j - 131072)] = (_Float16)Wr[j - 131072];
    else                 ws[OFF_WCH + (j - 262144)] = (_Float16)Wc[j - 262144];
  }
}

// ---------------------------------------------------------------- K1: Q/K projection, split-fp16 MFMA (3 products)
// grid (256, 2) x 256 thr. y=0: Q = input@Wq^T+bq ; y=1: K = prev@Wk^T+bk. 4 waves x 16 rows.
__global__ __launch_bounds__(256) void k1_proj(
    const float* __restrict__ input, const float* __restrict__ prev,
    const float* __restrict__ bq, const float* __restrict__ bk,
    _Float16* __restrict__ ws)
{
  const int which = blockIdx.y;
  const float* x = which ? prev : input;
  const _Float16* Wh = ws + (which ? OFF_WKH : OFF_WQH);
  const _Float16* Wl = ws + (which ? OFF_WKL : OFF_WQL);
  const float* bias = which ? bk : bq;
  _Float16* out = ws + (which ? OFF_K : OFF_Q);

  const int tid = threadIdx.x;
  const int wave = tid >> 6, l = tid & 63;
  const int lr = l & 15, lg = l >> 4;
  const int row0 = blockIdx.x * 64 + wave * 16;

  // A-frags: x[row0+lr][ks*32 + lg*8 + j], split hi/lo
  const float* xrow = x + (size_t)(row0 + lr) * 256 + lg * 8;
  half8 xh[8], xl[8];
#pragma unroll
  for (int ks = 0; ks < 8; ++ks) {
    floatx4 a = *(const floatx4*)(xrow + ks * 32);
    floatx4 b = *(const floatx4*)(xrow + ks * 32 + 4);
    half8 h, lo;
#pragma unroll
    for (int j = 0; j < 4; ++j) {
      h[j]     = (_Float16)a[j]; lo[j]     = (_Float16)(a[j] - (float)h[j]);
      h[4 + j] = (_Float16)b[j]; lo[4 + j] = (_Float16)(b[j] - (float)h[4 + j]);
    }
    xh[ks] = h; xl[ks] = lo;
  }

#pragma unroll 1
  for (int nt = 0; nt < 8; ++nt) {
    const _Float16* wph = Wh + (size_t)(nt * 16 + lr) * 256 + lg * 8;
    const _Float16* wpl = Wl + (size_t)(nt * 16 + lr) * 256 + lg * 8;
    floatx4 acc = {0.f, 0.f, 0.f, 0.f};
#pragma unroll
    for (int ks = 0; ks < 8; ++ks) {
      half8 wh = *(const half8*)(wph + ks * 32);
      half8 wl = *(const half8*)(wpl + ks * 32);
      acc = MFMA16(xh[ks], wh, acc);
      acc = MFMA16(xl[ks], wh, acc);
      acc = MFMA16(xh[ks], wl, acc);
    }
    float bv = bias[nt * 16 + lr];
#pragma unroll
    for (int j = 0; j < 4; ++j) {
      // C layout: row = lg*4+j, col = lr (m89-verified)
      out[(size_t)(row0 + lg * 4 + j) * 128 + nt * 16 + lr] = (_Float16)(acc[j] + bv);
    }
  }
}

// ---------------------------------------------------------------- K2: fused GRU gates -> new_memory
// grid 512 x 64 thr (1 wave, 32 rows). r-pass -> t=sigma(r)*m in swizzled LDS -> u+c pass -> combine.
__global__ __launch_bounds__(64, 1) void k2_gates(
    const float* __restrict__ input, const float* __restrict__ prev,
    const float* __restrict__ bu, const float* __restrict__ br,
    const float* __restrict__ bc, const _Float16* __restrict__ ws,
    float* __restrict__ out0)
{
  __shared__ char tlds[32 * 256 * 2];   // t = sigma(r)*m, fp16, XOR-swizzled
  const int l = threadIdx.x;
  const int lr = l & 15, lg = l >> 4;
  const int row0 = blockIdx.x * 32;

  // A-frags for combined = [input | prev], K=512 (ks 0..7 input, 8..15 prev)
  half8 ah[2][16];
#pragma unroll
  for (int mt = 0; mt < 2; ++mt) {
    const float* xr = input + (size_t)(row0 + mt * 16 + lr) * 256 + lg * 8;
    const float* mr = prev  + (size_t)(row0 + mt * 16 + lr) * 256 + lg * 8;
#pragma unroll
    for (int ks = 0; ks < 8; ++ks) {
      floatx4 a = *(const floatx4*)(xr + ks * 32);
      floatx4 b = *(const floatx4*)(xr + ks * 32 + 4);
      half8 h;
#pragma unroll
      for (int j = 0; j < 4; ++j) { h[j] = (_Float16)a[j]; h[4 + j] = (_Float16)b[j]; }
      ah[mt][ks] = h;
    }
#pragma unroll
    for (int ks = 0; ks < 8; ++ks) {
      floatx4 a = *(const floatx4*)(mr + ks * 32);
      floatx4 b = *(const floatx4*)(mr + ks * 32 + 4);
      half8 h;
#pragma unroll
      for (int j = 0; j < 4; ++j) { h[j] = (_Float16)a[j]; h[4 + j] = (_Float16)b[j]; }
      ah[mt][8 + ks] = h;
    }
  }
  const _Float16* Wr_ = ws + OFF_WRH;
  const _Float16* Wu_ = ws + OFF_WUH;
  const _Float16* Wc_ = ws + OFF_WCH;

  // ---- reset-gate pass
#pragma unroll 1
  for (int nt = 0; nt < 16; ++nt) {
    floatx4 acc0 = {0.f, 0.f, 0.f, 0.f}, acc1 = {0.f, 0.f, 0.f, 0.f};
    const _Float16* wp = Wr_ + (size_t)(nt * 16 + lr) * 512 + lg * 8;
#pragma unroll
    for (int ks = 0; ks < 16; ++ks) {
      half8 w = *(const half8*)(wp + ks * 32);
      acc0 = MFMA16(ah[0][ks], w, acc0);
      acc1 = MFMA16(ah[1][ks], w, acc1);
    }
    float bv = br[nt * 16 + lr];
    int col = nt * 16 + lr;
#pragma unroll
    for (int mt = 0; mt < 2; ++mt) {
      floatx4 acc = mt ? acc1 : acc0;
#pragma unroll
      for (int j = 0; j < 4; ++j) {
        int row = mt * 16 + lg * 4 + j;
        float rg = 1.f / (1.f + __expf(-(acc[j] + bv)));
        float mv = prev[(size_t)(row0 + row) * 256 + col];
        int byteoff = ((row * 256 + col) * 2) ^ ((row & 7) << 4);
        *(_Float16*)(tlds + byteoff) = (_Float16)(rg * mv);
      }
    }
  }
  __syncthreads();

  // ---- update-gate + candidate pass
#pragma unroll 1
  for (int nt = 0; nt < 16; ++nt) {
    floatx4 aU0 = {0.f,0.f,0.f,0.f}, aU1 = {0.f,0.f,0.f,0.f};
    floatx4 aC0 = {0.f,0.f,0.f,0.f}, aC1 = {0.f,0.f,0.f,0.f};
    const _Float16* wu = Wu_ + (size_t)(nt * 16 + lr) * 512 + lg * 8;
    const _Float16* wc = Wc_ + (size_t)(nt * 16 + lr) * 512 + lg * 8;
#pragma unroll
    for (int ks = 0; ks < 16; ++ks) {
      half8 wuf = *(const half8*)(wu + ks * 32);
      aU0 = MFMA16(ah[0][ks], wuf, aU0);
      aU1 = MFMA16(ah[1][ks], wuf, aU1);
      half8 wcf = *(const half8*)(wc + ks * 32);
      half8 a0, a1;
      if (ks < 8) { a0 = ah[0][ks]; a1 = ah[1][ks]; }
      else {
        int base0 = (lr * 512 + (ks - 8) * 64 + lg * 16) ^ ((lr & 7) << 4);
        int base1 = ((16 + lr) * 512 + (ks - 8) * 64 + lg * 16) ^ ((lr & 7) << 4);
        a0 = *(const half8*)(tlds + base0);
        a1 = *(const half8*)(tlds + base1);
      }
      aC0 = MFMA16(a0, wcf, aC0);
      aC1 = MFMA16(a1, wcf, aC1);
    }
    int col = nt * 16 + lr;
    float bvu = bu[col], bvc = bc[col];
#pragma unroll
    for (int mt = 0; mt < 2; ++mt) {
      floatx4 aU = mt ? aU1 : aU0;
      floatx4 aC = mt ? aC1 : aC0;
#pragma unroll
      for (int j = 0; j < 4; ++j) {
        int row = mt * 16 + lg * 4 + j;
        float ug = 1.f / (1.f + __expf(-(aU[j] + bvu)));
        float e2 = __expf(2.f * (aC[j] + bvc));
        float cg = (e2 - 1.f) / (e2 + 1.f);        // tanh
        float mv = prev[(size_t)(row0 + row) * 256 + col];
        out0[(size_t)(row0 + row) * 256 + col] = (1.f - ug) * mv + ug * cg;
      }
    }
  }
}

// ---------------------------------------------------------------- K3: attention scores + softmax (2-pass recompute)
// grid (32, 8) x 256 thr; wave handles 16 q-rows x 2048 keys. No max-subtraction (scores |s| << 88).
__global__ __launch_bounds__(256) void k3_attn(
    const _Float16* __restrict__ ws, float* __restrict__ out1)
{
  const int b = blockIdx.y;
  const int tid = threadIdx.x;
  const int wave = tid >> 6, l = tid & 63;
  const int lr = l & 15, lg = l >> 4;
  const int q0 = blockIdx.x * 64 + wave * 16;

  const _Float16* Q  = ws + OFF_Q + ((size_t)b * 2048 + q0) * 128;
  const _Float16* Kp = ws + OFF_K + (size_t)b * 2048 * 128;

  half8 qf[4];
#pragma unroll
  for (int ks = 0; ks < 4; ++ks)
    qf[ks] = *(const half8*)(Q + (size_t)lr * 128 + ks * 32 + lg * 8);

  float se0 = 0.f, se1 = 0.f, se2 = 0.f, se3 = 0.f;
#pragma unroll 1
  for (int kt = 0; kt < 128; kt += 2) {          // 2 key-tiles in flight to pipeline MFMA
    floatx4 a0 = {0.f,0.f,0.f,0.f}, a1 = {0.f,0.f,0.f,0.f};
    const _Float16* k0p = Kp + (size_t)(kt * 16 + lr) * 128 + lg * 8;
    const _Float16* k1p = k0p + 16 * 128;
#pragma unroll
    for (int ks = 0; ks < 4; ++ks) {
      a0 = MFMA16(qf[ks], *(const half8*)(k0p + ks * 32), a0);
      a1 = MFMA16(qf[ks], *(const half8*)(k1p + ks * 32), a1);
    }
    se0 += __expf(a0[0]) + __expf(a1[0]);
    se1 += __expf(a0[1]) + __expf(a1[1]);
    se2 += __expf(a0[2]) + __expf(a1[2]);
    se3 += __expf(a0[3]) + __expf(a1[3]);
  }
  // reduce across the 16 lanes (lr) sharing each q-row
#pragma unroll
  for (int m = 1; m < 16; m <<= 1) {
    se0 += __shfl_xor(se0, m);
    se1 += __shfl_xor(se1, m);
    se2 += __shfl_xor(se2, m);
    se3 += __shfl_xor(se3, m);
  }
  const float inv0 = 1.f / se0, inv1 = 1.f / se1, inv2 = 1.f / se2, inv3 = 1.f / se3;

  float* orow = out1 + ((size_t)b * 2048 + q0) * 2048;
#pragma unroll 1
  for (int kt = 0; kt < 128; kt += 2) {
    floatx4 a0 = {0.f,0.f,0.f,0.f}, a1 = {0.f,0.f,0.f,0.f};
    const _Float16* k0p = Kp + (size_t)(kt * 16 + lr) * 128 + lg * 8;
    const _Float16* k1p = k0p + 16 * 128;
#pragma unroll
    for (int ks = 0; ks < 4; ++ks) {
      a0 = MFMA16(qf[ks], *(const half8*)(k0p + ks * 32), a0);
      a1 = MFMA16(qf[ks], *(const half8*)(k1p + ks * 32), a1);
    }
    float* o0 = orow + (size_t)(lg * 4) * 2048 + kt * 16 + lr;
    o0[0 * 2048]      = __expf(a0[0]) * inv0;
    o0[1 * 2048]      = __expf(a0[1]) * inv1;
    o0[2 * 2048]      = __expf(a0[2]) * inv2;
    o0[3 * 2048]      = __expf(a0[3]) * inv3;
    o0[0 * 2048 + 16] = __expf(a1[0]) * inv0;
    o0[1 * 2048 + 16] = __expf(a1[1]) * inv1;
    o0[2 * 2048 + 16] = __expf(a1[2]) * inv2;
    o0[3 * 2048 + 16] = __expf(a1[3]) * inv3;
  }
}

// ----------------------------------------------------------------
extern "C" void kernel_launch(void* const* d_in, const int* in_sizes, int n_in,
                              void* d_out, int out_size, void* d_ws, size_t ws_size,
                              hipStream_t stream)
{
  const float* input = (const float*)d_in[0];
  const float* prev  = (const float*)d_in[1];
  const float* Wq = (const float*)d_in[2];
  const float* bq = (const float*)d_in[3];
  const float* Wk = (const float*)d_in[4];
  const float* bk = (const float*)d_in[5];
  // d_in[6], d_in[7] = Wv, bv -- dead in reference, skipped
  const float* Wu = (const float*)d_in[8];
  const float* bu = (const float*)d_in[9];
  const float* Wr = (const float*)d_in[10];
  const float* br = (const float*)d_in[11];
  const float* Wc = (const float*)d_in[12];
  const float* bc = (const float*)d_in[13];

  float* out0 = (float*)d_out;                       // new_memory [8,2048,256]
  float* out1 = out0 + (size_t)8 * 2048 * 256;       // attention_probs [8,2048,2048]
  _Float16* ws = (_Float16*)d_ws;                    // needs 9,437,184 bytes

  hipLaunchKernelGGL(k0_convert, dim3(1792), dim3(256), 0, stream, Wq, Wk, Wu, Wr, Wc, ws);
  hipLaunchKernelGGL(k1_proj,    dim3(256, 2), dim3(256), 0, stream, input, prev, bq, bk, ws);
  hipLaunchKernelGGL(k2_gates,   dim3(512), dim3(64), 0, stream, input, prev, bu, br, bc, ws, out0);
  hipLaunchKernelGGL(k3_attn,    dim3(32, 8), dim3(256), 0, stream, ws, out1);
}

// Round 2
// 215.419 us; speedup vs baseline: 1.6211x; 1.6211x over previous
//
#include <hip/hip_runtime.h>

// DynamicMemoryCell: B=8, N=2048, IN=256, MEM=256, CTX=128
// out0 = new_memory [8,2048,256] f32 ; out1 = attention_probs [8,2048,2048] f32
// Skip Wv/value/context entirely (dead in reference).

typedef _Float16 half8 __attribute__((ext_vector_type(8)));
typedef float floatx4 __attribute__((ext_vector_type(4)));

#define MFMA16(a, b, c) __builtin_amdgcn_mfma_f32_16x16x32_f16((a), (b), (c), 0, 0, 0)

// ws layout (units: _Float16)
#define OFF_WQH 0
#define OFF_WQL 32768
#define OFF_WKH 65536
#define OFF_WKL 98304
#define OFF_WUH 131072
#define OFF_WRH 262144
#define OFF_WCH 393216
#define OFF_Q   524288
#define OFF_K   2621440
// total = 4718592 halves = 9,437,184 bytes

// ---------------------------------------------------------------- K0: weights fp32 -> fp16 (hi/lo split for Wq/Wk)
__global__ __launch_bounds__(256) void k0_convert(
    const float* __restrict__ Wq, const float* __restrict__ Wk,
    const float* __restrict__ Wu, const float* __restrict__ Wr,
    const float* __restrict__ Wc, _Float16* __restrict__ ws)
{
  int i = blockIdx.x * 256 + threadIdx.x;   // grid covers 458752 exactly
  if (i < 32768) {
    float w = Wq[i];
    _Float16 h = (_Float16)w;
    ws[OFF_WQH + i] = h;
    ws[OFF_WQL + i] = (_Float16)(w - (float)h);
  } else if (i < 65536) {
    int j = i - 32768;
    float w = Wk[j];
    _Float16 h = (_Float16)w;
    ws[OFF_WKH + j] = h;
    ws[OFF_WKL + j] = (_Float16)(w - (float)h);
  } else {
    int j = i - 65536;                       // 0 .. 393215
    if (j < 131072)      ws[OFF_WUH + j]            = (_Float16)Wu[j];
    else if (j < 262144) ws[OFF_WRH + (j - 131072)] = (_Float16)Wr[j - 131072];
    else                 ws[OFF_WCH + (j - 262144)] = (_Float16)Wc[j - 262144];
  }
}

// ---------------------------------------------------------------- K1: Q/K projection, split-fp16 MFMA (3 products)
// grid (256, 2) x 256 thr. y=0: Q = input@Wq^T+bq ; y=1: K = prev@Wk^T+bk. 4 waves x 16 rows.
__global__ __launch_bounds__(256) void k1_proj(
    const float* __restrict__ input, const float* __restrict__ prev,
    const float* __restrict__ bq, const float* __restrict__ bk,
    _Float16* __restrict__ ws)
{
  const int which = blockIdx.y;
  const float* x = which ? prev : input;
  const _Float16* Wh = ws + (which ? OFF_WKH : OFF_WQH);
  const _Float16* Wl = ws + (which ? OFF_WKL : OFF_WQL);
  const float* bias = which ? bk : bq;
  _Float16* out = ws + (which ? OFF_K : OFF_Q);

  const int tid = threadIdx.x;
  const int wave = tid >> 6, l = tid & 63;
  const int lr = l & 15, lg = l >> 4;
  const int row0 = blockIdx.x * 64 + wave * 16;

  // A-frags: x[row0+lr][ks*32 + lg*8 + j], split hi/lo
  const float* xrow = x + (size_t)(row0 + lr) * 256 + lg * 8;
  half8 xh[8], xl[8];
#pragma unroll
  for (int ks = 0; ks < 8; ++ks) {
    floatx4 a = *(const floatx4*)(xrow + ks * 32);
    floatx4 b = *(const floatx4*)(xrow + ks * 32 + 4);
    half8 h, lo;
#pragma unroll
    for (int j = 0; j < 4; ++j) {
      h[j]     = (_Float16)a[j]; lo[j]     = (_Float16)(a[j] - (float)h[j]);
      h[4 + j] = (_Float16)b[j]; lo[4 + j] = (_Float16)(b[j] - (float)h[4 + j]);
    }
    xh[ks] = h; xl[ks] = lo;
  }

#pragma unroll 1
  for (int nt = 0; nt < 8; ++nt) {
    const _Float16* wph = Wh + (size_t)(nt * 16 + lr) * 256 + lg * 8;
    const _Float16* wpl = Wl + (size_t)(nt * 16 + lr) * 256 + lg * 8;
    floatx4 acc = {0.f, 0.f, 0.f, 0.f};
#pragma unroll
    for (int ks = 0; ks < 8; ++ks) {
      half8 wh = *(const half8*)(wph + ks * 32);
      half8 wl = *(const half8*)(wpl + ks * 32);
      acc = MFMA16(xh[ks], wh, acc);
      acc = MFMA16(xl[ks], wh, acc);
      acc = MFMA16(xh[ks], wl, acc);
    }
    float bv = bias[nt * 16 + lr];
#pragma unroll
    for (int j = 0; j < 4; ++j) {
      // C layout: row = lg*4+j, col = lr (m89-verified)
      out[(size_t)(row0 + lg * 4 + j) * 128 + nt * 16 + lr] = (_Float16)(acc[j] + bv);
    }
  }
}

// ---------------------------------------------------------------- K2: fused GRU gates -> new_memory
// grid 512 x 256 thr (4 waves). 32 rows/block; waves SPLIT the output-column (nt) dim 4 ways.
// r-pass -> t=sigma(r)*m in swizzled LDS (shared across waves) -> u+c pass -> combine.
__global__ __launch_bounds__(256) void k2_gates(
    const float* __restrict__ input, const float* __restrict__ prev,
    const float* __restrict__ bu, const float* __restrict__ br,
    const float* __restrict__ bc, const _Float16* __restrict__ ws,
    float* __restrict__ out0)
{
  __shared__ char tlds[32 * 256 * 2];   // t = sigma(r)*m, fp16, XOR-swizzled
  const int tid = threadIdx.x;
  const int w = tid >> 6, l = tid & 63;
  const int lr = l & 15, lg = l >> 4;
  const int row0 = blockIdx.x * 32;

  // A-frags for combined = [input | prev], K=512 (ks 0..7 input, 8..15 prev)
  half8 ah[2][16];
#pragma unroll
  for (int mt = 0; mt < 2; ++mt) {
    const float* xr = input + (size_t)(row0 + mt * 16 + lr) * 256 + lg * 8;
    const float* mr = prev  + (size_t)(row0 + mt * 16 + lr) * 256 + lg * 8;
#pragma unroll
    for (int ks = 0; ks < 8; ++ks) {
      floatx4 a = *(const floatx4*)(xr + ks * 32);
      floatx4 b = *(const floatx4*)(xr + ks * 32 + 4);
      half8 h;
#pragma unroll
      for (int j = 0; j < 4; ++j) { h[j] = (_Float16)a[j]; h[4 + j] = (_Float16)b[j]; }
      ah[mt][ks] = h;
    }
#pragma unroll
    for (int ks = 0; ks < 8; ++ks) {
      floatx4 a = *(const floatx4*)(mr + ks * 32);
      floatx4 b = *(const floatx4*)(mr + ks * 32 + 4);
      half8 h;
#pragma unroll
      for (int j = 0; j < 4; ++j) { h[j] = (_Float16)a[j]; h[4 + j] = (_Float16)b[j]; }
      ah[mt][8 + ks] = h;
    }
  }
  const _Float16* Wr_ = ws + OFF_WRH;
  const _Float16* Wu_ = ws + OFF_WUH;
  const _Float16* Wc_ = ws + OFF_WCH;

  // ---- reset-gate pass: wave w handles nt = 4w .. 4w+3
#pragma unroll 1
  for (int i = 0; i < 4; ++i) {
    const int nt = w * 4 + i;
    floatx4 acc0 = {0.f, 0.f, 0.f, 0.f}, acc1 = {0.f, 0.f, 0.f, 0.f};
    const _Float16* wp = Wr_ + (size_t)(nt * 16 + lr) * 512 + lg * 8;
#pragma unroll
    for (int ks = 0; ks < 16; ++ks) {
      half8 wv = *(const half8*)(wp + ks * 32);
      acc0 = MFMA16(ah[0][ks], wv, acc0);
      acc1 = MFMA16(ah[1][ks], wv, acc1);
    }
    float bv = br[nt * 16 + lr];
    int col = nt * 16 + lr;
#pragma unroll
    for (int mt = 0; mt < 2; ++mt) {
      floatx4 acc = mt ? acc1 : acc0;
#pragma unroll
      for (int j = 0; j < 4; ++j) {
        int row = mt * 16 + lg * 4 + j;
        float rg = 1.f / (1.f + __expf(-(acc[j] + bv)));
        float mv = prev[(size_t)(row0 + row) * 256 + col];
        int byteoff = ((row * 256 + col) * 2) ^ ((row & 7) << 4);
        *(_Float16*)(tlds + byteoff) = (_Float16)(rg * mv);
      }
    }
  }
  __syncthreads();

  // ---- update-gate + candidate pass: wave w handles nt = 4w .. 4w+3
#pragma unroll 1
  for (int i = 0; i < 4; ++i) {
    const int nt = w * 4 + i;
    floatx4 aU0 = {0.f,0.f,0.f,0.f}, aU1 = {0.f,0.f,0.f,0.f};
    floatx4 aC0 = {0.f,0.f,0.f,0.f}, aC1 = {0.f,0.f,0.f,0.f};
    const _Float16* wu = Wu_ + (size_t)(nt * 16 + lr) * 512 + lg * 8;
    const _Float16* wc = Wc_ + (size_t)(nt * 16 + lr) * 512 + lg * 8;
#pragma unroll
    for (int ks = 0; ks < 16; ++ks) {
      half8 wuf = *(const half8*)(wu + ks * 32);
      aU0 = MFMA16(ah[0][ks], wuf, aU0);
      aU1 = MFMA16(ah[1][ks], wuf, aU1);
      half8 wcf = *(const half8*)(wc + ks * 32);
      half8 a0, a1;
      if (ks < 8) { a0 = ah[0][ks]; a1 = ah[1][ks]; }
      else {
        int base0 = (lr * 512 + (ks - 8) * 64 + lg * 16) ^ ((lr & 7) << 4);
        int base1 = ((16 + lr) * 512 + (ks - 8) * 64 + lg * 16) ^ ((lr & 7) << 4);
        a0 = *(const half8*)(tlds + base0);
        a1 = *(const half8*)(tlds + base1);
      }
      aC0 = MFMA16(a0, wcf, aC0);
      aC1 = MFMA16(a1, wcf, aC1);
    }
    int col = nt * 16 + lr;
    float bvu = bu[col], bvc = bc[col];
#pragma unroll
    for (int mt = 0; mt < 2; ++mt) {
      floatx4 aU = mt ? aU1 : aU0;
      floatx4 aC = mt ? aC1 : aC0;
#pragma unroll
      for (int j = 0; j < 4; ++j) {
        int row = mt * 16 + lg * 4 + j;
        float ug = 1.f / (1.f + __expf(-(aU[j] + bvu)));
        float e2 = __expf(2.f * (aC[j] + bvc));
        float cg = (e2 - 1.f) / (e2 + 1.f);        // tanh
        float mv = prev[(size_t)(row0 + row) * 256 + col];
        out0[(size_t)(row0 + row) * 256 + col] = (1.f - ug) * mv + ug * cg;
      }
    }
  }
}

// ---------------------------------------------------------------- K3: attention scores + softmax (2-pass recompute)
// grid (64, 8) x 256 thr; block = 32 q-rows; 4 waves SPLIT the key range (512 keys each).
// Cross-wave denominator reduce via LDS. No max-subtraction (|s| <= ~25 << 88).
__global__ __launch_bounds__(256) void k3_attn(
    const _Float16* __restrict__ ws, float* __restrict__ out1)
{
  __shared__ float sums[4][32];
  const int b = blockIdx.y;
  const int tid = threadIdx.x;
  const int w = tid >> 6, l = tid & 63;
  const int lr = l & 15, lg = l >> 4;
  const int q0 = blockIdx.x * 32;

  const _Float16* Q  = ws + OFF_Q + ((size_t)b * 2048 + q0) * 128;
  const _Float16* Kp = ws + OFF_K + (size_t)b * 2048 * 128 + (size_t)w * 512 * 128;

  half8 qf[2][4];
#pragma unroll
  for (int qt = 0; qt < 2; ++qt)
#pragma unroll
    for (int ks = 0; ks < 4; ++ks)
      qf[qt][ks] = *(const half8*)(Q + (size_t)(qt * 16 + lr) * 128 + ks * 32 + lg * 8);

  float se0[4] = {0.f,0.f,0.f,0.f}, se1[4] = {0.f,0.f,0.f,0.f};
#pragma unroll 1
  for (int kt = 0; kt < 32; kt += 2) {
    const _Float16* k0p = Kp + (size_t)(kt * 16 + lr) * 128 + lg * 8;
    const _Float16* k1p = k0p + 16 * 128;
    half8 kf0[4], kf1[4];
#pragma unroll
    for (int ks = 0; ks < 4; ++ks) { kf0[ks] = *(const half8*)(k0p + ks * 32); kf1[ks] = *(const half8*)(k1p + ks * 32); }
    floatx4 a00 = {0.f,0.f,0.f,0.f}, a01 = {0.f,0.f,0.f,0.f};
    floatx4 a10 = {0.f,0.f,0.f,0.f}, a11 = {0.f,0.f,0.f,0.f};
#pragma unroll
    for (int ks = 0; ks < 4; ++ks) {
      a00 = MFMA16(qf[0][ks], kf0[ks], a00);
      a10 = MFMA16(qf[1][ks], kf0[ks], a10);
      a01 = MFMA16(qf[0][ks], kf1[ks], a01);
      a11 = MFMA16(qf[1][ks], kf1[ks], a11);
    }
#pragma unroll
    for (int j = 0; j < 4; ++j) {
      se0[j] += __expf(a00[j]) + __expf(a01[j]);
      se1[j] += __expf(a10[j]) + __expf(a11[j]);
    }
  }
  // reduce across the 16 lanes (lr) sharing each q-row
#pragma unroll
  for (int m = 1; m < 16; m <<= 1) {
#pragma unroll
    for (int j = 0; j < 4; ++j) { se0[j] += __shfl_xor(se0[j], m); se1[j] += __shfl_xor(se1[j], m); }
  }
  if (lr == 0) {
#pragma unroll
    for (int j = 0; j < 4; ++j) { sums[w][lg * 4 + j] = se0[j]; sums[w][16 + lg * 4 + j] = se1[j]; }
  }
  __syncthreads();
  float inv0[4], inv1[4];
#pragma unroll
  for (int j = 0; j < 4; ++j) {
    int r0 = lg * 4 + j, r1 = 16 + lg * 4 + j;
    inv0[j] = 1.f / (sums[0][r0] + sums[1][r0] + sums[2][r0] + sums[3][r0]);
    inv1[j] = 1.f / (sums[0][r1] + sums[1][r1] + sums[2][r1] + sums[3][r1]);
  }

  float* orow = out1 + ((size_t)b * 2048 + q0) * 2048 + w * 512;
#pragma unroll 1
  for (int kt = 0; kt < 32; kt += 2) {
    const _Float16* k0p = Kp + (size_t)(kt * 16 + lr) * 128 + lg * 8;
    const _Float16* k1p = k0p + 16 * 128;
    half8 kf0[4], kf1[4];
#pragma unroll
    for (int ks = 0; ks < 4; ++ks) { kf0[ks] = *(const half8*)(k0p + ks * 32); kf1[ks] = *(const half8*)(k1p + ks * 32); }
    floatx4 a00 = {0.f,0.f,0.f,0.f}, a01 = {0.f,0.f,0.f,0.f};
    floatx4 a10 = {0.f,0.f,0.f,0.f}, a11 = {0.f,0.f,0.f,0.f};
#pragma unroll
    for (int ks = 0; ks < 4; ++ks) {
      a00 = MFMA16(qf[0][ks], kf0[ks], a00);
      a10 = MFMA16(qf[1][ks], kf0[ks], a10);
      a01 = MFMA16(qf[0][ks], kf1[ks], a01);
      a11 = MFMA16(qf[1][ks], kf1[ks], a11);
    }
    float* o0 = orow + (size_t)(lg * 4) * 2048 + kt * 16 + lr;
    float* o1 = o0 + (size_t)16 * 2048;
#pragma unroll
    for (int j = 0; j < 4; ++j) {
      o0[(size_t)j * 2048]      = __expf(a00[j]) * inv0[j];
      o0[(size_t)j * 2048 + 16] = __expf(a01[j]) * inv0[j];
      o1[(size_t)j * 2048]      = __expf(a10[j]) * inv1[j];
      o1[(size_t)j * 2048 + 16] = __expf(a11[j]) * inv1[j];
    }
  }
}

// ----------------------------------------------------------------
extern "C" void kernel_launch(void* const* d_in, const int* in_sizes, int n_in,
                              void* d_out, int out_size, void* d_ws, size_t ws_size,
                              hipStream_t stream)
{
  const float* input = (const float*)d_in[0];
  const float* prev  = (const float*)d_in[1];
  const float* Wq = (const float*)d_in[2];
  const float* bq = (const float*)d_in[3];
  const float* Wk = (const float*)d_in[4];
  const float* bk = (const float*)d_in[5];
  // d_in[6], d_in[7] = Wv, bv -- dead in reference, skipped
  const float* Wu = (const float*)d_in[8];
  const float* bu = (const float*)d_in[9];
  const float* Wr = (const float*)d_in[10];
  const float* br = (const float*)d_in[11];
  const float* Wc = (const float*)d_in[12];
  const float* bc = (const float*)d_in[13];

  float* out0 = (float*)d_out;                       // new_memory [8,2048,256]
  float* out1 = out0 + (size_t)8 * 2048 * 256;       // attention_probs [8,2048,2048]
  _Float16* ws = (_Float16*)d_ws;                    // needs 9,437,184 bytes

  hipLaunchKernelGGL(k0_convert, dim3(1792), dim3(256), 0, stream, Wq, Wk, Wu, Wr, Wc, ws);
  hipLaunchKernelGGL(k1_proj,    dim3(256, 2), dim3(256), 0, stream, input, prev, bq, bk, ws);
  hipLaunchKernelGGL(k2_gates,   dim3(512), dim3(256), 0, stream, input, prev, bu, br, bc, ws, out0);
  hipLaunchKernelGGL(k3_attn,    dim3(64, 8), dim3(256), 0, stream, ws, out1);
}